// Round 6
// baseline (525.968 us; speedup 1.0000x reference)
//
#include <hip/hip_runtime.h>

#define N_NODES 100000
#define IN_DIM 64
#define EMB 128
#define N_EDGES 1600000
#define BN_EPS 1e-5f

#define SCAN_ELEMS (N_NODES + 1)        // 100001
#define S1_EPB 1024
#define S1_BLOCKS ((SCAN_ELEMS + S1_EPB - 1) / S1_EPB)   // 98

// ---- workspace layout (bytes) ----
#define WS_ROWSTART 0
#define WS_GSUM     400128
#define WS_GSUM2    400640
#define WS_CURSOR   401152
#define WS_BSUM     801280
#define WS_PAIRS    801792
#define WS_ZERO_BYTES 401152

// ---------------- 1) histogram of dst (4 edges/thread) ----------------
__global__ __launch_bounds__(256) void hist_kernel(
    const int* __restrict__ ei, int* __restrict__ rowstart)
{
    int e0 = (blockIdx.x * 256 + threadIdx.x) * 4;
    if (e0 >= N_EDGES) return;
    int4 d4 = *(const int4*)(ei + N_EDGES + e0);
    atomicAdd(&rowstart[1 + d4.x], 1);
    atomicAdd(&rowstart[1 + d4.y], 1);
    atomicAdd(&rowstart[1 + d4.z], 1);
    atomicAdd(&rowstart[1 + d4.w], 1);
}

// ---------------- 2a) per-block reduce of counts ----------------
__global__ __launch_bounds__(256) void scan1_kernel(
    const int* __restrict__ rowstart, int* __restrict__ bsum)
{
    __shared__ int red[256];
    const int t = threadIdx.x;
    const int base = blockIdx.x * S1_EPB + t * 4;
    int s = 0;
    #pragma unroll
    for (int k = 0; k < 4; ++k) {
        int idx = base + k;
        if (idx < SCAN_ELEMS) s += rowstart[idx];
    }
    red[t] = s;
    __syncthreads();
    for (int off = 128; off > 0; off >>= 1) {
        if (t < off) red[t] += red[t + off];
        __syncthreads();
    }
    if (t == 0) bsum[blockIdx.x] = red[0];
}

// ---------------- 2b) exclusive scan of block sums ----------------
__global__ __launch_bounds__(128) void scan2_kernel(int* __restrict__ bsum)
{
    __shared__ int buf[128];
    const int t = threadIdx.x;
    buf[t] = (t < S1_BLOCKS) ? bsum[t] : 0;
    __syncthreads();
    for (int off = 1; off < 128; off <<= 1) {
        int v = (t >= off) ? buf[t - off] : 0;
        __syncthreads();
        buf[t] += v;
        __syncthreads();
    }
    if (t < S1_BLOCKS) bsum[t] = (t > 0) ? buf[t - 1] : 0;
}

// ---------------- 2c) block-local inclusive scan + offset ----------------
__global__ __launch_bounds__(256) void scan3_kernel(
    int* __restrict__ rowstart, int* __restrict__ cursor,
    const int* __restrict__ bsum)
{
    __shared__ int tsum[256];
    const int t = threadIdx.x;
    const int base = blockIdx.x * S1_EPB + t * 4;
    int c0 = 0, c1 = 0, c2 = 0, c3 = 0;
    if (base + 0 < SCAN_ELEMS) c0 = rowstart[base + 0];
    if (base + 1 < SCAN_ELEMS) c1 = rowstart[base + 1];
    if (base + 2 < SCAN_ELEMS) c2 = rowstart[base + 2];
    if (base + 3 < SCAN_ELEMS) c3 = rowstart[base + 3];
    const int i0 = c0, i1 = i0 + c1, i2 = i1 + c2, i3 = i2 + c3;
    tsum[t] = i3;
    __syncthreads();
    for (int off = 1; off < 256; off <<= 1) {
        int v = (t >= off) ? tsum[t - off] : 0;
        __syncthreads();
        tsum[t] += v;
        __syncthreads();
    }
    const int boff = bsum[blockIdx.x] + tsum[t] - i3;
    const int r0 = boff + i0, r1 = boff + i1, r2 = boff + i2, r3 = boff + i3;
    if (base + 0 < SCAN_ELEMS) rowstart[base + 0] = r0;
    if (base + 1 < SCAN_ELEMS) rowstart[base + 1] = r1;
    if (base + 2 < SCAN_ELEMS) rowstart[base + 2] = r2;
    if (base + 3 < SCAN_ELEMS) rowstart[base + 3] = r3;
    if (base + 0 < N_NODES) cursor[base + 0] = r0;
    if (base + 1 < N_NODES) cursor[base + 1] = r1;
    if (base + 2 < N_NODES) cursor[base + 2] = r2;
    if (base + 3 < N_NODES) cursor[base + 3] = r3;
}

// ---------------- 3) fill (src, w) pairs (4 edges/thread) ----------------
__global__ __launch_bounds__(256) void fill_kernel(
    const int* __restrict__ ei, const float* __restrict__ ew,
    int* __restrict__ cursor, float2* __restrict__ pairs)
{
    int e0 = (blockIdx.x * 256 + threadIdx.x) * 4;
    if (e0 >= N_EDGES) return;
    int4   s4 = *(const int4*)(ei + e0);
    int4   d4 = *(const int4*)(ei + N_EDGES + e0);
    float4 w4 = *(const float4*)(ew + e0);
    int p0 = atomicAdd(&cursor[d4.x], 1);
    int p1 = atomicAdd(&cursor[d4.y], 1);
    int p2 = atomicAdd(&cursor[d4.z], 1);
    int p3 = atomicAdd(&cursor[d4.w], 1);
    pairs[p0] = make_float2(__int_as_float(s4.x), w4.x);
    pairs[p1] = make_float2(__int_as_float(s4.y), w4.y);
    pairs[p2] = make_float2(__int_as_float(s4.z), w4.z);
    pairs[p3] = make_float2(__int_as_float(s4.w), w4.w);
}

// ---------------- 4) fused gather + (agg+x)@W1+b1 + BN partial stats ----------------
// Gather lane map: e = lane>>4 (edge slot 0..3), f = lane&15 (float4 feat group).
// One dwordx4 wave-instr covers 4 edges' full 64-feat rows (1 KB).
#define B1_NPW 5   // nodes per wave -> grid = 100000/(4*5) = 5000 blocks
__global__ __launch_bounds__(256) void mlp1_kernel(
    const float* __restrict__ x,
    const int* __restrict__ rowstart,
    const float2* __restrict__ pairs,
    const float* __restrict__ W1,   // [64,128] row-major
    const float* __restrict__ b1,
    float* __restrict__ h,          // [N,128]
    float* __restrict__ gsum, float* __restrict__ gsum2)
{
    __shared__ float w1s[IN_DIM][EMB];       // 32 KB
    __shared__ float4 rowbuf4[4][16];        // per-wave row (64 feats as 16 float4)
    __shared__ float red[4][2][EMB];         // per-wave col partials

    const int tid  = threadIdx.x;
    const int lane = tid & 63;
    const int wid  = tid >> 6;
    const int lane64 = lane + 64;
    const int e = lane >> 4;     // edge slot
    const int f = lane & 15;     // feat quad

    const float4* __restrict__ x4 = (const float4*)x;

    for (int i = tid; i < IN_DIM * EMB; i += 256)
        w1s[i >> 7][i & 127] = W1[i];
    const float bl0 = b1[lane], bl1 = b1[lane64];
    __syncthreads();   // w1s ready

    float s0 = 0.f, s20 = 0.f, s1 = 0.f, s21 = 0.f;
    const int node0 = (blockIdx.x * 4 + wid) * B1_NPW;

    for (int r = 0; r < B1_NPW; ++r) {
        const int n  = node0 + r;
        const int jb = rowstart[n];
        const int je = rowstart[n + 1];

        float4 acc = make_float4(0.f, 0.f, 0.f, 0.f);
        for (int j0 = jb; j0 < je; j0 += 64) {
            const int cnt = min(64, je - j0);
            float2 p = (lane < cnt) ? pairs[j0 + lane] : make_float2(0.f, 0.f);
            int   psrc = __float_as_int(p.x);
            float pw   = p.y;
            const int nch = (cnt + 3) >> 2;   // chunks of 4 edges
            #pragma unroll 4
            for (int c = 0; c < nch; ++c) {
                int   s = __shfl(psrc, c * 4 + e);
                float w = __shfl(pw,   c * 4 + e);
                float4 xv = x4[(size_t)s * 16 + f];
                acc.x += w * xv.x; acc.y += w * xv.y;
                acc.z += w * xv.z; acc.w += w * xv.w;
            }
        }
        // reduce across edge slots (lanes differing in bits 4,5)
        acc.x += __shfl_xor(acc.x, 16); acc.y += __shfl_xor(acc.y, 16);
        acc.z += __shfl_xor(acc.z, 16); acc.w += __shfl_xor(acc.w, 16);
        acc.x += __shfl_xor(acc.x, 32); acc.y += __shfl_xor(acc.y, 32);
        acc.z += __shfl_xor(acc.z, 32); acc.w += __shfl_xor(acc.w, 32);

        if (e == 0) {   // lanes 0..15 write the full row (+ self term)
            float4 xs = x4[(size_t)n * 16 + f];
            rowbuf4[wid][f] = make_float4(acc.x + xs.x, acc.y + xs.y,
                                          acc.z + xs.z, acc.w + xs.w);
        }

        // GEMV: lane computes cols lane, lane+64 (same-wave LDS write->read)
        float a0 = bl0, a1 = bl1;
        const float4* rb4 = &rowbuf4[wid][0];
        #pragma unroll
        for (int kg = 0; kg < 16; ++kg) {
            float4 rv = rb4[kg];
            int k = kg * 4;
            a0 += rv.x * w1s[k][lane]   + rv.y * w1s[k+1][lane]
                + rv.z * w1s[k+2][lane] + rv.w * w1s[k+3][lane];
            a1 += rv.x * w1s[k][lane64]   + rv.y * w1s[k+1][lane64]
                + rv.z * w1s[k+2][lane64] + rv.w * w1s[k+3][lane64];
        }
        h[(size_t)n * EMB + lane]   = a0;
        h[(size_t)n * EMB + lane64] = a1;
        s0 += a0; s20 += a0 * a0;
        s1 += a1; s21 += a1 * a1;
    }

    red[wid][0][lane] = s0;  red[wid][0][lane64] = s1;
    red[wid][1][lane] = s20; red[wid][1][lane64] = s21;
    __syncthreads();
    if (tid < EMB) {
        float t0 = red[0][0][tid] + red[1][0][tid] + red[2][0][tid] + red[3][0][tid];
        float t1 = red[0][1][tid] + red[1][1][tid] + red[2][1][tid] + red[3][1][tid];
        atomicAdd(&gsum[tid],  t0);
        atomicAdd(&gsum2[tid], t1);
    }
}

// ---------------- 5) out = relu(BN(h)) @ W2 + b2 (in-place on h) ----------------
// W2 column in 128 VGPRs/thread; nbuf read via broadcast b128 (conflict-free).
#define E_ROWS 80
__global__ __launch_bounds__(256, 2) void mlp2_kernel(
    float* __restrict__ hio,
    const float* __restrict__ gsum, const float* __restrict__ gsum2,
    const float* __restrict__ gamma, const float* __restrict__ beta,
    const float* __restrict__ W2,   // [128,128] row-major
    const float* __restrict__ b2)
{
    __shared__ float nbuf[8][EMB];    // 4 KB

    const int tid = threadIdx.x;
    const int col = tid & 127;
    const int rh  = tid >> 7;         // 0/1: which 4-row half

    float w[EMB];
    #pragma unroll
    for (int k = 0; k < EMB; ++k) w[k] = W2[k * EMB + col];

    const float invN = 1.0f / (float)N_NODES;
    float mean = gsum[col] * invN;
    float var  = gsum2[col] * invN - mean * mean;
    float inv  = rsqrtf(var + BN_EPS);
    float a    = gamma[col] * inv;
    float bb   = beta[col] - mean * a;
    float bj   = b2[col];

    const int row0 = blockIdx.x * E_ROWS;
    for (int it = 0; it < E_ROWS / 8; ++it) {
        const int rbase = row0 + it * 8;
        __syncthreads();   // protect nbuf reuse from previous chunk
        #pragma unroll
        for (int rr = 0; rr < 4; ++rr) {
            int lr = rh * 4 + rr;
            float hv = hio[(size_t)(rbase + lr) * EMB + col];
            nbuf[lr][col] = fmaxf(hv * a + bb, 0.f);
        }
        __syncthreads();
        #pragma unroll
        for (int rr = 0; rr < 4; ++rr) {
            const int lr = rh * 4 + rr;
            const float4* nb4 = (const float4*)&nbuf[lr][0];
            float acc = bj;
            #pragma unroll
            for (int kg = 0; kg < 32; ++kg) {
                float4 nv = nb4[kg];   // broadcast: all lanes same address
                acc += nv.x * w[kg*4+0] + nv.y * w[kg*4+1]
                     + nv.z * w[kg*4+2] + nv.w * w[kg*4+3];
            }
            hio[(size_t)(rbase + lr) * EMB + col] = acc;
        }
    }
}

extern "C" void kernel_launch(void* const* d_in, const int* in_sizes, int n_in,
                              void* d_out, int out_size, void* d_ws, size_t ws_size,
                              hipStream_t stream)
{
    const float* x     = (const float*)d_in[0];
    const int*   ei    = (const int*)d_in[1];   // int32 [2,E]
    const float* ew    = (const float*)d_in[3];
    const float* W1    = (const float*)d_in[4];
    const float* b1    = (const float*)d_in[5];
    const float* gamma = (const float*)d_in[6];
    const float* beta  = (const float*)d_in[7];
    const float* W2    = (const float*)d_in[8];
    const float* b2    = (const float*)d_in[9];

    char* ws = (char*)d_ws;
    int*    rowstart = (int*)(ws + WS_ROWSTART);
    int*    cursor   = (int*)(ws + WS_CURSOR);
    float*  gsum     = (float*)(ws + WS_GSUM);
    float*  gsum2    = (float*)(ws + WS_GSUM2);
    int*    bsum     = (int*)(ws + WS_BSUM);
    float2* pairs    = (float2*)(ws + WS_PAIRS);
    float*  h        = (float*)d_out;

    hipMemsetAsync(d_ws, 0, WS_ZERO_BYTES, stream);

    hist_kernel<<<(N_EDGES / 4 + 255) / 256, 256, 0, stream>>>(ei, rowstart);
    scan1_kernel<<<S1_BLOCKS, 256, 0, stream>>>(rowstart, bsum);
    scan2_kernel<<<1, 128, 0, stream>>>(bsum);
    scan3_kernel<<<S1_BLOCKS, 256, 0, stream>>>(rowstart, cursor, bsum);
    fill_kernel<<<(N_EDGES / 4 + 255) / 256, 256, 0, stream>>>(ei, ew, cursor, pairs);
    mlp1_kernel<<<N_NODES / (4 * B1_NPW), 256, 0, stream>>>(x, rowstart, pairs, W1, b1, h, gsum, gsum2);
    mlp2_kernel<<<N_NODES / E_ROWS, 256, 0, stream>>>(h, gsum, gsum2, gamma, beta, W2, b2);
}

// Round 7
// 500.854 us; speedup vs baseline: 1.0501x; 1.0501x over previous
//
#include <hip/hip_runtime.h>
#include <hip/hip_fp16.h>

#define N_NODES 100000
#define IN_DIM 64
#define EMB 128
#define N_EDGES 1600000
#define BN_EPS 1e-5f

#define SCAN_ELEMS (N_NODES + 1)        // 100001
#define S1_EPB 1024
#define S1_BLOCKS ((SCAN_ELEMS + S1_EPB - 1) / S1_EPB)   // 98

// ---- workspace layout (bytes) ----
#define WS_ROWSTART 0
#define WS_GSUM     400128
#define WS_GSUM2    400640
#define WS_CURSOR   401152
#define WS_BSUM     801280
#define WS_PAIRS    801792
#define WS_X16      13601792                 // pairs + 12.8 MB
#define WS_NEED_F16 26401792ULL              // x16 + 12.8 MB
#define WS_ZERO_BYTES 401152

// ---------------- 1) histogram of dst (4 edges/thread) ----------------
__global__ __launch_bounds__(256) void hist_kernel(
    const int* __restrict__ ei, int* __restrict__ rowstart)
{
    int e0 = (blockIdx.x * 256 + threadIdx.x) * 4;
    if (e0 >= N_EDGES) return;
    int4 d4 = *(const int4*)(ei + N_EDGES + e0);
    atomicAdd(&rowstart[1 + d4.x], 1);
    atomicAdd(&rowstart[1 + d4.y], 1);
    atomicAdd(&rowstart[1 + d4.z], 1);
    atomicAdd(&rowstart[1 + d4.w], 1);
}

// ---------------- 1b) x -> fp16 sidecar ----------------
__global__ __launch_bounds__(256) void cvt_kernel(
    const float4* __restrict__ x4, uint2* __restrict__ x16)
{
    int i = blockIdx.x * 256 + threadIdx.x;   // 1.6M threads, 4 floats each
    if (i >= N_NODES * IN_DIM / 4) return;
    float4 v = x4[i];
    __half2 lo = __floats2half2_rn(v.x, v.y);
    __half2 hi = __floats2half2_rn(v.z, v.w);
    uint2 u;
    u.x = *(unsigned int*)&lo;
    u.y = *(unsigned int*)&hi;
    x16[i] = u;
}

// ---------------- 2a) per-block reduce of counts ----------------
__global__ __launch_bounds__(256) void scan1_kernel(
    const int* __restrict__ rowstart, int* __restrict__ bsum)
{
    __shared__ int red[256];
    const int t = threadIdx.x;
    const int base = blockIdx.x * S1_EPB + t * 4;
    int s = 0;
    #pragma unroll
    for (int k = 0; k < 4; ++k) {
        int idx = base + k;
        if (idx < SCAN_ELEMS) s += rowstart[idx];
    }
    red[t] = s;
    __syncthreads();
    for (int off = 128; off > 0; off >>= 1) {
        if (t < off) red[t] += red[t + off];
        __syncthreads();
    }
    if (t == 0) bsum[blockIdx.x] = red[0];
}

// ---------------- 2b) exclusive scan of block sums ----------------
__global__ __launch_bounds__(128) void scan2_kernel(int* __restrict__ bsum)
{
    __shared__ int buf[128];
    const int t = threadIdx.x;
    buf[t] = (t < S1_BLOCKS) ? bsum[t] : 0;
    __syncthreads();
    for (int off = 1; off < 128; off <<= 1) {
        int v = (t >= off) ? buf[t - off] : 0;
        __syncthreads();
        buf[t] += v;
        __syncthreads();
    }
    if (t < S1_BLOCKS) bsum[t] = (t > 0) ? buf[t - 1] : 0;
}

// ---------------- 2c) block-local inclusive scan + offset ----------------
__global__ __launch_bounds__(256) void scan3_kernel(
    int* __restrict__ rowstart, int* __restrict__ cursor,
    const int* __restrict__ bsum)
{
    __shared__ int tsum[256];
    const int t = threadIdx.x;
    const int base = blockIdx.x * S1_EPB + t * 4;
    int c0 = 0, c1 = 0, c2 = 0, c3 = 0;
    if (base + 0 < SCAN_ELEMS) c0 = rowstart[base + 0];
    if (base + 1 < SCAN_ELEMS) c1 = rowstart[base + 1];
    if (base + 2 < SCAN_ELEMS) c2 = rowstart[base + 2];
    if (base + 3 < SCAN_ELEMS) c3 = rowstart[base + 3];
    const int i0 = c0, i1 = i0 + c1, i2 = i1 + c2, i3 = i2 + c3;
    tsum[t] = i3;
    __syncthreads();
    for (int off = 1; off < 256; off <<= 1) {
        int v = (t >= off) ? tsum[t - off] : 0;
        __syncthreads();
        tsum[t] += v;
        __syncthreads();
    }
    const int boff = bsum[blockIdx.x] + tsum[t] - i3;
    const int r0 = boff + i0, r1 = boff + i1, r2 = boff + i2, r3 = boff + i3;
    if (base + 0 < SCAN_ELEMS) rowstart[base + 0] = r0;
    if (base + 1 < SCAN_ELEMS) rowstart[base + 1] = r1;
    if (base + 2 < SCAN_ELEMS) rowstart[base + 2] = r2;
    if (base + 3 < SCAN_ELEMS) rowstart[base + 3] = r3;
    if (base + 0 < N_NODES) cursor[base + 0] = r0;
    if (base + 1 < N_NODES) cursor[base + 1] = r1;
    if (base + 2 < N_NODES) cursor[base + 2] = r2;
    if (base + 3 < N_NODES) cursor[base + 3] = r3;
}

// ---------------- 3) fill (src, w) pairs (4 edges/thread) ----------------
__global__ __launch_bounds__(256) void fill_kernel(
    const int* __restrict__ ei, const float* __restrict__ ew,
    int* __restrict__ cursor, float2* __restrict__ pairs)
{
    int e0 = (blockIdx.x * 256 + threadIdx.x) * 4;
    if (e0 >= N_EDGES) return;
    int4   s4 = *(const int4*)(ei + e0);
    int4   d4 = *(const int4*)(ei + N_EDGES + e0);
    float4 w4 = *(const float4*)(ew + e0);
    int p0 = atomicAdd(&cursor[d4.x], 1);
    int p1 = atomicAdd(&cursor[d4.y], 1);
    int p2 = atomicAdd(&cursor[d4.z], 1);
    int p3 = atomicAdd(&cursor[d4.w], 1);
    pairs[p0] = make_float2(__int_as_float(s4.x), w4.x);
    pairs[p1] = make_float2(__int_as_float(s4.y), w4.y);
    pairs[p2] = make_float2(__int_as_float(s4.z), w4.z);
    pairs[p3] = make_float2(__int_as_float(s4.w), w4.w);
}

// ---------------- 4) fused gather + (agg+x)@W1+b1 + BN partial stats ----------------
// Round-5 structure (lane = feature, 16-deep unrolled edge loads, 2 acc chains).
// F16 variant gathers from the fp16 sidecar (128 B rows -> half the L2-miss bytes).
#define B1_NPW 5   // nodes per wave -> grid = 100000/(4*5) = 5000 blocks
template<bool F16>
__global__ __launch_bounds__(256) void mlp1_kernel(
    const float* __restrict__ x,
    const __half* __restrict__ x16,
    const int* __restrict__ rowstart,
    const float2* __restrict__ pairs,
    const float* __restrict__ W1,   // [64,128] row-major
    const float* __restrict__ b1,
    float* __restrict__ h,          // [N,128]
    float* __restrict__ gsum, float* __restrict__ gsum2)
{
    __shared__ float w1s[IN_DIM][EMB];     // 32 KB
    __shared__ float rowbuf[4][IN_DIM];    // per-wave row
    __shared__ float red[4][2][EMB];       // per-wave col partials

    const int tid  = threadIdx.x;
    const int lane = tid & 63;
    const int wid  = tid >> 6;
    const int lane64 = lane + 64;

    for (int i = tid; i < IN_DIM * EMB; i += 256)
        w1s[i >> 7][i & 127] = W1[i];
    const float bl0 = b1[lane], bl1 = b1[lane64];
    __syncthreads();   // w1s ready

    float s0 = 0.f, s20 = 0.f, s1 = 0.f, s21 = 0.f;
    const int node0 = (blockIdx.x * 4 + wid) * B1_NPW;

    for (int r = 0; r < B1_NPW; ++r) {
        const int n  = node0 + r;
        const int jb = rowstart[n];
        const int je = rowstart[n + 1];

        float accA = x[(size_t)n * IN_DIM + lane];   // self term fp32, (1+eps)=1
        float accB = 0.f;
        for (int j0 = jb; j0 < je; j0 += 64) {
            const int cnt = min(64, je - j0);
            float2 p = (lane < cnt) ? pairs[j0 + lane] : make_float2(0.f, 0.f);
            int   psrc = __float_as_int(p.x);
            float pw   = p.y;
            const int nch = (cnt + 15) >> 4;
            for (int c = 0; c < nch; ++c) {
                const int base = c * 16;
                #pragma unroll
                for (int t = 0; t < 16; t += 2) {
                    int   sA = __shfl(psrc, base + t);
                    float wA = __shfl(pw,   base + t);
                    int   sB = __shfl(psrc, base + t + 1);
                    float wB = __shfl(pw,   base + t + 1);
                    if (F16) {
                        accA += wA * __half2float(x16[(size_t)sA * IN_DIM + lane]);
                        accB += wB * __half2float(x16[(size_t)sB * IN_DIM + lane]);
                    } else {
                        accA += wA * x[(size_t)sA * IN_DIM + lane];
                        accB += wB * x[(size_t)sB * IN_DIM + lane];
                    }
                }
            }
        }
        rowbuf[wid][lane] = accA + accB;

        float a0 = bl0, a1 = bl1;
        const float4* rb4 = (const float4*)rowbuf[wid];
        #pragma unroll
        for (int kg = 0; kg < 16; ++kg) {
            float4 rv = rb4[kg];
            int k = kg * 4;
            a0 += rv.x * w1s[k][lane]   + rv.y * w1s[k+1][lane]
                + rv.z * w1s[k+2][lane] + rv.w * w1s[k+3][lane];
            a1 += rv.x * w1s[k][lane64]   + rv.y * w1s[k+1][lane64]
                + rv.z * w1s[k+2][lane64] + rv.w * w1s[k+3][lane64];
        }
        h[(size_t)n * EMB + lane]   = a0;
        h[(size_t)n * EMB + lane64] = a1;
        s0 += a0; s20 += a0 * a0;
        s1 += a1; s21 += a1 * a1;
    }

    red[wid][0][lane] = s0;  red[wid][0][lane64] = s1;
    red[wid][1][lane] = s20; red[wid][1][lane64] = s21;
    __syncthreads();
    if (tid < EMB) {
        float t0 = red[0][0][tid] + red[1][0][tid] + red[2][0][tid] + red[3][0][tid];
        float t1 = red[0][1][tid] + red[1][1][tid] + red[2][1][tid] + red[3][1][tid];
        atomicAdd(&gsum[tid],  t0);
        atomicAdd(&gsum2[tid], t1);
    }
}

// ---------------- 5) out = relu(BN(h)) @ W2 + b2 (in-place on h) ----------------
#define E_ROWS 80
__global__ __launch_bounds__(256, 2) void mlp2_kernel(
    float* __restrict__ hio,
    const float* __restrict__ gsum, const float* __restrict__ gsum2,
    const float* __restrict__ gamma, const float* __restrict__ beta,
    const float* __restrict__ W2,   // [128,128] row-major
    const float* __restrict__ b2)
{
    __shared__ float nbuf[8][EMB];    // 4 KB

    const int tid = threadIdx.x;
    const int col = tid & 127;
    const int rh  = tid >> 7;

    float w[EMB];
    #pragma unroll
    for (int k = 0; k < EMB; ++k) w[k] = W2[k * EMB + col];

    const float invN = 1.0f / (float)N_NODES;
    float mean = gsum[col] * invN;
    float var  = gsum2[col] * invN - mean * mean;
    float inv  = rsqrtf(var + BN_EPS);
    float a    = gamma[col] * inv;
    float bb   = beta[col] - mean * a;
    float bj   = b2[col];

    const int row0 = blockIdx.x * E_ROWS;
    for (int it = 0; it < E_ROWS / 8; ++it) {
        const int rbase = row0 + it * 8;
        __syncthreads();
        #pragma unroll
        for (int rr = 0; rr < 4; ++rr) {
            int lr = rh * 4 + rr;
            float hv = hio[(size_t)(rbase + lr) * EMB + col];
            nbuf[lr][col] = fmaxf(hv * a + bb, 0.f);
        }
        __syncthreads();
        #pragma unroll
        for (int rr = 0; rr < 4; ++rr) {
            const int lr = rh * 4 + rr;
            const float4* nb4 = (const float4*)&nbuf[lr][0];
            float acc = bj;
            #pragma unroll
            for (int kg = 0; kg < 32; ++kg) {
                float4 nv = nb4[kg];   // broadcast: all lanes same address
                acc += nv.x * w[kg*4+0] + nv.y * w[kg*4+1]
                     + nv.z * w[kg*4+2] + nv.w * w[kg*4+3];
            }
            hio[(size_t)(rbase + lr) * EMB + col] = acc;
        }
    }
}

extern "C" void kernel_launch(void* const* d_in, const int* in_sizes, int n_in,
                              void* d_out, int out_size, void* d_ws, size_t ws_size,
                              hipStream_t stream)
{
    const float* x     = (const float*)d_in[0];
    const int*   ei    = (const int*)d_in[1];   // int32 [2,E]
    const float* ew    = (const float*)d_in[3];
    const float* W1    = (const float*)d_in[4];
    const float* b1    = (const float*)d_in[5];
    const float* gamma = (const float*)d_in[6];
    const float* beta  = (const float*)d_in[7];
    const float* W2    = (const float*)d_in[8];
    const float* b2    = (const float*)d_in[9];

    char* ws = (char*)d_ws;
    int*    rowstart = (int*)(ws + WS_ROWSTART);
    int*    cursor   = (int*)(ws + WS_CURSOR);
    float*  gsum     = (float*)(ws + WS_GSUM);
    float*  gsum2    = (float*)(ws + WS_GSUM2);
    int*    bsum     = (int*)(ws + WS_BSUM);
    float2* pairs    = (float2*)(ws + WS_PAIRS);
    __half* x16      = (__half*)(ws + WS_X16);
    float*  h        = (float*)d_out;

    const bool use16 = (ws_size >= WS_NEED_F16);

    hipMemsetAsync(d_ws, 0, WS_ZERO_BYTES, stream);

    hist_kernel<<<(N_EDGES / 4 + 255) / 256, 256, 0, stream>>>(ei, rowstart);
    if (use16)
        cvt_kernel<<<(N_NODES * IN_DIM / 4 + 255) / 256, 256, 0, stream>>>(
            (const float4*)x, (uint2*)x16);
    scan1_kernel<<<S1_BLOCKS, 256, 0, stream>>>(rowstart, bsum);
    scan2_kernel<<<1, 128, 0, stream>>>(bsum);
    scan3_kernel<<<S1_BLOCKS, 256, 0, stream>>>(rowstart, cursor, bsum);
    fill_kernel<<<(N_EDGES / 4 + 255) / 256, 256, 0, stream>>>(ei, ew, cursor, pairs);
    if (use16)
        mlp1_kernel<true><<<N_NODES / (4 * B1_NPW), 256, 0, stream>>>(
            x, x16, rowstart, pairs, W1, b1, h, gsum, gsum2);
    else
        mlp1_kernel<false><<<N_NODES / (4 * B1_NPW), 256, 0, stream>>>(
            x, x16, rowstart, pairs, W1, b1, h, gsum, gsum2);
    mlp2_kernel<<<N_NODES / E_ROWS, 256, 0, stream>>>(h, gsum, gsum2, gamma, beta, W2, b2);
}